// Round 1
// baseline (344.851 us; speedup 1.0000x reference)
//
#include <hip/hip_runtime.h>

typedef _Float16 half8 __attribute__((ext_vector_type(8)));
typedef _Float16 half4 __attribute__((ext_vector_type(4)));
typedef float floatx4 __attribute__((ext_vector_type(4)));

#define MFMA_F16 __builtin_amdgcn_mfma_f32_16x16x32_f16

// B=2, H=16, L=8192, D=64, WINDOW=512, nw=16, FADE=64
// Grid: 4096 blocks = qt(8) x [bh(32) x n(16)]; qt is the SLOW dim so the 8
// q-tile blocks of one window are 512 apart -> same XCD under %8 round-robin.
__global__ __launch_bounds__(256) void swa_kernel(
    const float* __restrict__ Q, const float* __restrict__ K,
    const float* __restrict__ V, const int* __restrict__ pid,
    float* __restrict__ Out)
{
    __shared__ __align__(16) _Float16 lq[64][72];     // Q tile, rope'd, f16 (pitch 144B = 9x16B)
    __shared__ __align__(16) _Float16 lk[32][72];     // K chunk, rope'd
    __shared__ __align__(16) _Float16 lvt[64][40];    // V^T chunk (pitch 80B = 5x16B)
    __shared__ __align__(16) _Float16 lp[4][16][40];  // per-wave P buffer

    const int bid = blockIdx.x;
    const int qt  = bid >> 9;        // 0..7 q-tile within window
    const int wl  = bid & 511;
    const int n   = wl & 15;         // window index
    const int bh  = wl >> 4;         // b*16+h
    const long long winrow = (long long)bh * 8192 + n * 512;
    const float* Qb = Q + (winrow + qt * 64) * 64;
    const float* Kb = K + winrow * 64;
    const float* Vb = V + winrow * 64;
    float* Ob = Out + (winrow + qt * 64) * 64;

    const int tid  = threadIdx.x;
    const int lane = tid & 63;
    const int wv   = tid >> 6;       // wave 0..3
    const int l15  = lane & 15;
    const int quad = lane >> 4;

    const float NEG  = -1e30f;
    const float CS   = 0.125f * 1.44269504088896f;   // 1/sqrt(D) * log2(e)
    const float FREQ = -0.41524101186092f;           // -log2(10000)/32

    // ---- stage Q tile with RoPE (64 rows x 64 d), each thread: 1 row-quarter pair ----
    {
        int q  = tid >> 2;           // 0..63
        int dg = tid & 3;
        int d0 = dg * 8;             // 0,8,16,24
        const float* src = Qb + q * 64;
        float pos = (float)pid[n * 512 + qt * 64 + q];
        float4 a0 = *(const float4*)(src + d0);
        float4 a1 = *(const float4*)(src + d0 + 4);
        float4 b0 = *(const float4*)(src + d0 + 32);
        float4 b1 = *(const float4*)(src + d0 + 36);
        float lo[8] = {a0.x,a0.y,a0.z,a0.w,a1.x,a1.y,a1.z,a1.w};
        float hi[8] = {b0.x,b0.y,b0.z,b0.w,b1.x,b1.y,b1.z,b1.w};
        half8 wlo, whi;
        #pragma unroll
        for (int i = 0; i < 8; ++i) {
            float ang = pos * __builtin_exp2f((float)(d0 + i) * FREQ);
            float sn, cn;
            __sincosf(ang, &sn, &cn);
            wlo[i] = (_Float16)(lo[i] * cn - hi[i] * sn);
            whi[i] = (_Float16)(hi[i] * cn + lo[i] * sn);
        }
        *(half8*)&lq[q][d0]      = wlo;
        *(half8*)&lq[q][d0 + 32] = whi;
    }
    __syncthreads();
    // Q A-fragments: lane holds A[m=lane&15][k=quad*8+j]
    const half8 qf0 = *(const half8*)&lq[wv * 16 + l15][quad * 8];
    const half8 qf1 = *(const half8*)&lq[wv * 16 + l15][32 + quad * 8];

    floatx4 o[4]; // O accum: 4 dv-tiles, C-layout (row=quad*4+r, col=lane&15)
    #pragma unroll
    for (int vt = 0; vt < 4; ++vt) o[vt] = (floatx4){0.f, 0.f, 0.f, 0.f};
    float mr[4] = {NEG, NEG, NEG, NEG};
    float lr[4] = {0.f, 0.f, 0.f, 0.f};

    for (int kc = 0; kc < 16; ++kc) {
        __syncthreads();   // previous iteration's lk/lvt reads done
        // ---- stage K chunk (32 keys) with RoPE ----
        {
            int key = tid >> 3;      // 0..31
            int dg  = tid & 7;
            int d0  = dg * 4;        // 0..28
            const float* src = Kb + (kc * 32 + key) * 64;
            float4 a = *(const float4*)(src + d0);
            float4 b = *(const float4*)(src + d0 + 32);
            float pos = (float)pid[n * 512 + kc * 32 + key];
            float lo[4] = {a.x, a.y, a.z, a.w};
            float hi[4] = {b.x, b.y, b.z, b.w};
            half4 wlo, whi;
            #pragma unroll
            for (int i = 0; i < 4; ++i) {
                float ang = pos * __builtin_exp2f((float)(d0 + i) * FREQ);
                float sn, cn;
                __sincosf(ang, &sn, &cn);
                wlo[i] = (_Float16)(lo[i] * cn - hi[i] * sn);
                whi[i] = (_Float16)(hi[i] * cn + lo[i] * sn);
            }
            *(half4*)&lk[key][d0]      = wlo;
            *(half4*)&lk[key][d0 + 32] = whi;
        }
        // ---- stage V^T chunk: thread owns one dv column, 8 keys -> one b128 write ----
        {
            int dv = tid & 63;
            int kg = tid >> 6;       // 0..3
            half8 v;
            #pragma unroll
            for (int i = 0; i < 8; ++i)
                v[i] = (_Float16)Vb[(kc * 32 + kg * 8 + i) * 64 + dv];
            *(half8*)&lvt[dv][kg * 8] = v;
        }
        __syncthreads();

        // ---- QK^T: S tiles 16q x 16k x2, K B-frag: lane holds B[k=quad*8+j][n=lane&15]
        half8 kf00 = *(const half8*)&lk[l15][quad * 8];
        half8 kf01 = *(const half8*)&lk[l15][32 + quad * 8];
        half8 kf10 = *(const half8*)&lk[16 + l15][quad * 8];
        half8 kf11 = *(const half8*)&lk[16 + l15][32 + quad * 8];

        floatx4 s0 = {0.f,0.f,0.f,0.f}, s1 = {0.f,0.f,0.f,0.f};
        s0 = MFMA_F16(qf0, kf00, s0, 0, 0, 0);
        s0 = MFMA_F16(qf1, kf01, s0, 0, 0, 0);
        s1 = MFMA_F16(qf0, kf10, s1, 0, 0, 0);
        s1 = MFMA_F16(qf1, kf11, s1, 0, 0, 0);

        // ---- online softmax (exp2 domain), rows = quad*4+r, cols across 16 lanes
        float alpha[4];
        #pragma unroll
        for (int r = 0; r < 4; ++r) {
            float t0 = s0[r] * CS, t1 = s1[r] * CS;
            float v = fmaxf(t0, t1);
            v = fmaxf(v, __shfl_xor(v, 1));
            v = fmaxf(v, __shfl_xor(v, 2));
            v = fmaxf(v, __shfl_xor(v, 4));
            v = fmaxf(v, __shfl_xor(v, 8));
            float mn = fmaxf(mr[r], v);
            alpha[r] = __builtin_exp2f(mr[r] - mn);
            mr[r] = mn;
            float p0 = __builtin_exp2f(t0 - mn);
            float p1 = __builtin_exp2f(t1 - mn);
            float ss = p0 + p1;
            ss += __shfl_xor(ss, 1);
            ss += __shfl_xor(ss, 2);
            ss += __shfl_xor(ss, 4);
            ss += __shfl_xor(ss, 8);
            lr[r] = lr[r] * alpha[r] + ss;
            // P to LDS in [q][key] layout (C-layout -> A-layout round trip)
            lp[wv][quad * 4 + r][l15]      = (_Float16)p0;
            lp[wv][quad * 4 + r][16 + l15] = (_Float16)p1;
        }
        #pragma unroll
        for (int vt = 0; vt < 4; ++vt) {
            #pragma unroll
            for (int r = 0; r < 4; ++r) o[vt][r] *= alpha[r];
        }
        // ---- PV: A = P(16x32) one frag, B = V^T frags per dv-tile
        half8 pf = *(const half8*)&lp[wv][l15][quad * 8];
        #pragma unroll
        for (int vt = 0; vt < 4; ++vt) {
            half8 vf = *(const half8*)&lvt[vt * 16 + l15][quad * 8];
            o[vt] = MFMA_F16(pf, vf, o[vt], 0, 0, 0);
        }
    }

    // ---- epilogue: /l, fade scale, store fp32 ----
    #pragma unroll
    for (int vt = 0; vt < 4; ++vt) {
        #pragma unroll
        for (int r = 0; r < 4; ++r) {
            int rowl = wv * 16 + quad * 4 + r;     // row within 64-q tile
            int j = qt * 64 + rowl;                // row within window
            float w;
            if (n == 0 || n == 15)  w = 1.0f;
            else if (j < 64)        w = (float)j * (1.0f / 63.0f);
            else if (j >= 448)      w = (float)(511 - j) * (1.0f / 63.0f);
            else                    w = 1.0f;
            float sc = w / (w + 1e-8f);
            Ob[rowl * 64 + vt * 16 + l15] = o[vt][r] / lr[r] * sc;
        }
    }
}

extern "C" void kernel_launch(void* const* d_in, const int* in_sizes, int n_in,
                              void* d_out, int out_size, void* d_ws, size_t ws_size,
                              hipStream_t stream) {
    const float* q   = (const float*)d_in[0];
    const float* k   = (const float*)d_in[1];
    const float* v   = (const float*)d_in[2];
    const int*   pid = (const int*)d_in[3];
    float* out = (float*)d_out;
    (void)in_sizes; (void)n_in; (void)out_size; (void)d_ws; (void)ws_size;
    // B*H*nw = 512 windows, 8 q-tiles each
    swa_kernel<<<dim3(4096), dim3(256), 0, stream>>>(q, k, v, pid, out);
}

// Round 2
// 288.191 us; speedup vs baseline: 1.1966x; 1.1966x over previous
//
#include <hip/hip_runtime.h>

typedef _Float16 half8 __attribute__((ext_vector_type(8)));
typedef _Float16 half4 __attribute__((ext_vector_type(4)));
typedef float floatx4 __attribute__((ext_vector_type(4)));

#define MFMA_F16 __builtin_amdgcn_mfma_f32_16x16x32_f16
#define FREQ (-0.41524101186092f)   // -log2(10000)/32

__device__ __forceinline__ void async_copy16(const void* g, void* l) {
    __builtin_amdgcn_global_load_lds(
        (const __attribute__((address_space(1))) unsigned int*)g,
        (__attribute__((address_space(3))) unsigned int*)l, 16, 0, 0);
}

// ---------------- pass 0: cos/sin table [8192][64] (cos 0..31, sin 32..63) ----
__global__ __launch_bounds__(256) void table_k(const int* __restrict__ pid,
                                               float* __restrict__ tab) {
    int idx = blockIdx.x * 256 + threadIdx.x;   // 0..262143
    int p = idx >> 5, d = idx & 31;
    float pos = (float)pid[p];
    float ang = pos * __builtin_exp2f((float)d * FREQ);
    float s, c;
    __sincosf(ang, &s, &c);
    tab[p * 64 + d] = c;
    tab[p * 64 + 32 + d] = s;
}

// ---------------- pass 1: rope K -> f16, swizzled cols (col' = col ^ (l&7)) ---
__global__ __launch_bounds__(256) void kprep(const float* __restrict__ K,
                                             const float* __restrict__ tab,
                                             _Float16* __restrict__ Kr) {
    int t = threadIdx.x;
    long long row = (long long)blockIdx.x * 64 + (t >> 2);
    int l = (int)(row & 8191);
    int d0 = (t & 3) * 8;
    const float* src = K + row * 64;
    float4 a0 = *(const float4*)(src + d0);
    float4 a1 = *(const float4*)(src + d0 + 4);
    float4 b0 = *(const float4*)(src + 32 + d0);
    float4 b1 = *(const float4*)(src + 36 + d0);
    const float* tp = tab + l * 64 + d0;
    float4 c0 = *(const float4*)(tp);
    float4 c1 = *(const float4*)(tp + 4);
    float4 s0 = *(const float4*)(tp + 32);
    float4 s1 = *(const float4*)(tp + 36);
    float lo[8] = {a0.x,a0.y,a0.z,a0.w,a1.x,a1.y,a1.z,a1.w};
    float hi[8] = {b0.x,b0.y,b0.z,b0.w,b1.x,b1.y,b1.z,b1.w};
    float cs[8] = {c0.x,c0.y,c0.z,c0.w,c1.x,c1.y,c1.z,c1.w};
    float sn[8] = {s0.x,s0.y,s0.z,s0.w,s1.x,s1.y,s1.z,s1.w};
    half8 wlo, whi;
    #pragma unroll
    for (int i = 0; i < 8; ++i) {
        wlo[i] = (_Float16)(lo[i] * cs[i] - hi[i] * sn[i]);
        whi[i] = (_Float16)(hi[i] * cs[i] + lo[i] * sn[i]);
    }
    int cl = d0 >> 3;
    int sw = l & 7;
    _Float16* dst = Kr + row * 64;
    *(half8*)(dst + (cl ^ sw) * 8)       = wlo;
    *(half8*)(dst + ((cl + 4) ^ sw) * 8) = whi;
}

// ---------------- pass 2: V -> f16 transposed chunks, swizzled --------------
// Vt[(win*16+kc)*2048 + dv*32 + (k8 ^ ((dv>>1)&3))*8 + i] = V[key=k8*8+i][dv]
__global__ __launch_bounds__(256) void vprep(const float* __restrict__ V,
                                             _Float16* __restrict__ Vt) {
    __shared__ _Float16 lsv[32 * 68];
    int blk = blockIdx.x;            // win*16 + kc
    int t = threadIdx.x;
    long long rowbase = (long long)(blk >> 4) * 512 + (blk & 15) * 32;
    {
        int key = t >> 3, d0 = (t & 7) * 8;
        const float* src = V + (rowbase + key) * 64 + d0;
        float4 a = *(const float4*)(src);
        float4 b = *(const float4*)(src + 4);
        half8 h;
        h[0]=(_Float16)a.x; h[1]=(_Float16)a.y; h[2]=(_Float16)a.z; h[3]=(_Float16)a.w;
        h[4]=(_Float16)b.x; h[5]=(_Float16)b.y; h[6]=(_Float16)b.z; h[7]=(_Float16)b.w;
        *(half8*)&lsv[key * 68 + d0] = h;
    }
    __syncthreads();
    int dv = t >> 2, k8 = t & 3;
    half8 v;
    #pragma unroll
    for (int i = 0; i < 8; ++i) v[i] = lsv[(k8 * 8 + i) * 68 + dv];
    *(half8*)(Vt + (long long)blk * 2048 + dv * 32 + ((k8 ^ ((dv >> 1) & 3)) * 8)) = v;
}

// ---------------- pass 3: attention ----------------------------------------
__global__ __launch_bounds__(256) void swa2(const float* __restrict__ Q,
                                            const _Float16* __restrict__ Kr,
                                            const _Float16* __restrict__ Vt,
                                            const float* __restrict__ tab,
                                            float* __restrict__ Out) {
    __shared__ __align__(16) _Float16 lq[64 * 72];
    __shared__ __align__(16) _Float16 lk[32 * 64];
    __shared__ __align__(16) _Float16 lvt[64 * 32];
    __shared__ __align__(16) _Float16 lp[4][16 * 40];

    const int bid = blockIdx.x;
    const int qt = bid >> 9;
    const int wl = bid & 511;
    const int n = wl & 15, bh = wl >> 4;
    const int win = bh * 16 + n;
    const long long winrow = (long long)bh * 8192 + n * 512;
    const float* Qb = Q + (winrow + qt * 64) * 64;
    const _Float16* Kb = Kr + winrow * 64;
    const _Float16* Vb = Vt + (long long)win * 32768;
    float* Ob = Out + (winrow + qt * 64) * 64;

    const int tid = threadIdx.x, lane = tid & 63, wv = tid >> 6;
    const int l15 = lane & 15, quad = lane >> 4;
    const float CS = 0.125f * 1.44269504088896f;

    // ---- Q stage: rope from table, fold CS, f16 ----
    {
        int q = tid >> 2, d0 = (tid & 3) * 8;
        int l = n * 512 + qt * 64 + q;
        const float* src = Qb + q * 64;
        float4 a0 = *(const float4*)(src + d0);
        float4 a1 = *(const float4*)(src + d0 + 4);
        float4 b0 = *(const float4*)(src + 32 + d0);
        float4 b1 = *(const float4*)(src + 36 + d0);
        const float* tp = tab + l * 64 + d0;
        float4 c0 = *(const float4*)(tp);
        float4 c1 = *(const float4*)(tp + 4);
        float4 s0 = *(const float4*)(tp + 32);
        float4 s1 = *(const float4*)(tp + 36);
        float lo[8] = {a0.x,a0.y,a0.z,a0.w,a1.x,a1.y,a1.z,a1.w};
        float hi[8] = {b0.x,b0.y,b0.z,b0.w,b1.x,b1.y,b1.z,b1.w};
        float cs[8] = {c0.x,c0.y,c0.z,c0.w,c1.x,c1.y,c1.z,c1.w};
        float sn[8] = {s0.x,s0.y,s0.z,s0.w,s1.x,s1.y,s1.z,s1.w};
        half8 wlo, whi;
        #pragma unroll
        for (int i = 0; i < 8; ++i) {
            wlo[i] = (_Float16)((lo[i] * cs[i] - hi[i] * sn[i]) * CS);
            whi[i] = (_Float16)((hi[i] * cs[i] + lo[i] * sn[i]) * CS);
        }
        *(half8*)&lq[q * 72 + d0]      = wlo;
        *(half8*)&lq[q * 72 + 32 + d0] = whi;
    }
    __syncthreads();
    const half8 qf0 = *(const half8*)&lq[(wv * 16 + l15) * 72 + quad * 8];
    const half8 qf1 = *(const half8*)&lq[(wv * 16 + l15) * 72 + 32 + quad * 8];

    floatx4 o[4], ol;
    #pragma unroll
    for (int vt = 0; vt < 4; ++vt) o[vt] = (floatx4){0.f, 0.f, 0.f, 0.f};
    ol = (floatx4){0.f, 0.f, 0.f, 0.f};

    half8 onesf;
    #pragma unroll
    for (int i = 0; i < 8; ++i) onesf[i] = (_Float16)1.0f;

    const int ksw0 = (quad ^ (l15 & 7)) * 8;         // K col'=quad
    const int ksw1 = ((quad + 4) ^ (l15 & 7)) * 8;   // K col'=quad+4
    const int vsw  = (quad ^ ((l15 >> 1) & 3)) * 8;  // V col'=quad

    for (int kc = 0; kc < 16; ++kc) {
        __syncthreads();   // prior iter's LDS reads complete
        async_copy16(Kb + kc * 2048 + tid * 8, &lk[tid * 8]);
        async_copy16(Vb + kc * 2048 + tid * 8, &lvt[tid * 8]);
        __syncthreads();   // compiler drains vmcnt before barrier

        half8 kf00 = *(const half8*)&lk[l15 * 64 + ksw0];
        half8 kf01 = *(const half8*)&lk[l15 * 64 + ksw1];
        half8 kf10 = *(const half8*)&lk[(16 + l15) * 64 + ksw0];
        half8 kf11 = *(const half8*)&lk[(16 + l15) * 64 + ksw1];

        floatx4 s0 = {0.f,0.f,0.f,0.f}, s1 = {0.f,0.f,0.f,0.f};
        s0 = MFMA_F16(qf0, kf00, s0, 0, 0, 0);
        s0 = MFMA_F16(qf1, kf01, s0, 0, 0, 0);
        s1 = MFMA_F16(qf0, kf10, s1, 0, 0, 0);
        s1 = MFMA_F16(qf1, kf11, s1, 0, 0, 0);

        // unnormalized softmax: scores pre-scaled for exp2, no max subtraction
        #pragma unroll
        for (int r = 0; r < 4; ++r) {
            float p0 = __builtin_exp2f(s0[r]);
            float p1 = __builtin_exp2f(s1[r]);
            lp[wv][(quad * 4 + r) * 40 + l15]      = (_Float16)p0;
            lp[wv][(quad * 4 + r) * 40 + 16 + l15] = (_Float16)p1;
        }
        half8 pf = *(const half8*)&lp[wv][l15 * 40 + quad * 8];
        ol = MFMA_F16(pf, onesf, ol, 0, 0, 0);   // row sums, replicated per lane
        #pragma unroll
        for (int vt = 0; vt < 4; ++vt) {
            half8 vf = *(const half8*)&lvt[(vt * 16 + l15) * 32 + vsw];
            o[vt] = MFMA_F16(pf, vf, o[vt], 0, 0, 0);
        }
    }

    // ---- epilogue: /l, fade scale, store ----
    #pragma unroll
    for (int r = 0; r < 4; ++r) {
        int rowl = wv * 16 + quad * 4 + r;
        int j = qt * 64 + rowl;
        float w;
        if (n == 0 || n == 15)  w = 1.0f;
        else if (j < 64)        w = (float)j * (1.0f / 63.0f);
        else if (j >= 448)      w = (float)(511 - j) * (1.0f / 63.0f);
        else                    w = 1.0f;
        float f = (w / (w + 1e-8f)) / ol[r];
        #pragma unroll
        for (int vt = 0; vt < 4; ++vt)
            Ob[rowl * 64 + vt * 16 + l15] = o[vt][r] * f;
    }
}

// ---------------- fallback (round-1 fused kernel) if ws too small -----------
__global__ __launch_bounds__(256) void swa_fb(
    const float* __restrict__ Q, const float* __restrict__ K,
    const float* __restrict__ V, const int* __restrict__ pid,
    float* __restrict__ Out)
{
    __shared__ __align__(16) _Float16 lq[64][72];
    __shared__ __align__(16) _Float16 lk[32][72];
    __shared__ __align__(16) _Float16 lvt[64][40];
    __shared__ __align__(16) _Float16 lp[4][16][40];

    const int bid = blockIdx.x;
    const int qt  = bid >> 9;
    const int wl  = bid & 511;
    const int n   = wl & 15;
    const int bh  = wl >> 4;
    const long long winrow = (long long)bh * 8192 + n * 512;
    const float* Qb = Q + (winrow + qt * 64) * 64;
    const float* Kb = K + winrow * 64;
    const float* Vb = V + winrow * 64;
    float* Ob = Out + (winrow + qt * 64) * 64;

    const int tid  = threadIdx.x;
    const int lane = tid & 63;
    const int wv   = tid >> 6;
    const int l15  = lane & 15;
    const int quad = lane >> 4;

    const float NEG  = -1e30f;
    const float CS   = 0.125f * 1.44269504088896f;

    {
        int q  = tid >> 2;
        int dg = tid & 3;
        int d0 = dg * 8;
        const float* src = Qb + q * 64;
        float pos = (float)pid[n * 512 + qt * 64 + q];
        float4 a0 = *(const float4*)(src + d0);
        float4 a1 = *(const float4*)(src + d0 + 4);
        float4 b0 = *(const float4*)(src + d0 + 32);
        float4 b1 = *(const float4*)(src + d0 + 36);
        float lo[8] = {a0.x,a0.y,a0.z,a0.w,a1.x,a1.y,a1.z,a1.w};
        float hi[8] = {b0.x,b0.y,b0.z,b0.w,b1.x,b1.y,b1.z,b1.w};
        half8 wlo, whi;
        #pragma unroll
        for (int i = 0; i < 8; ++i) {
            float ang = pos * __builtin_exp2f((float)(d0 + i) * FREQ);
            float sn, cn;
            __sincosf(ang, &sn, &cn);
            wlo[i] = (_Float16)(lo[i] * cn - hi[i] * sn);
            whi[i] = (_Float16)(hi[i] * cn + lo[i] * sn);
        }
        *(half8*)&lq[q][d0]      = wlo;
        *(half8*)&lq[q][d0 + 32] = whi;
    }
    __syncthreads();
    const half8 qf0 = *(const half8*)&lq[wv * 16 + l15][quad * 8];
    const half8 qf1 = *(const half8*)&lq[wv * 16 + l15][32 + quad * 8];

    floatx4 o[4];
    #pragma unroll
    for (int vt = 0; vt < 4; ++vt) o[vt] = (floatx4){0.f, 0.f, 0.f, 0.f};
    float mr[4] = {NEG, NEG, NEG, NEG};
    float lr[4] = {0.f, 0.f, 0.f, 0.f};

    for (int kc = 0; kc < 16; ++kc) {
        __syncthreads();
        {
            int key = tid >> 3;
            int dg  = tid & 7;
            int d0  = dg * 4;
            const float* src = Kb + (kc * 32 + key) * 64;
            float4 a = *(const float4*)(src + d0);
            float4 b = *(const float4*)(src + d0 + 32);
            float pos = (float)pid[n * 512 + kc * 32 + key];
            float lo[4] = {a.x, a.y, a.z, a.w};
            float hi[4] = {b.x, b.y, b.z, b.w};
            half4 wlo, whi;
            #pragma unroll
            for (int i = 0; i < 4; ++i) {
                float ang = pos * __builtin_exp2f((float)(d0 + i) * FREQ);
                float sn, cn;
                __sincosf(ang, &sn, &cn);
                wlo[i] = (_Float16)(lo[i] * cn - hi[i] * sn);
                whi[i] = (_Float16)(hi[i] * cn + lo[i] * sn);
            }
            *(half4*)&lk[key][d0]      = wlo;
            *(half4*)&lk[key][d0 + 32] = whi;
        }
        {
            int dv = tid & 63;
            int kg = tid >> 6;
            half8 v;
            #pragma unroll
            for (int i = 0; i < 8; ++i)
                v[i] = (_Float16)Vb[(kc * 32 + kg * 8 + i) * 64 + dv];
            *(half8*)&lvt[dv][kg * 8] = v;
        }
        __syncthreads();

        half8 kf00 = *(const half8*)&lk[l15][quad * 8];
        half8 kf01 = *(const half8*)&lk[l15][32 + quad * 8];
        half8 kf10 = *(const half8*)&lk[16 + l15][quad * 8];
        half8 kf11 = *(const half8*)&lk[16 + l15][32 + quad * 8];

        floatx4 s0 = {0.f,0.f,0.f,0.f}, s1 = {0.f,0.f,0.f,0.f};
        s0 = MFMA_F16(qf0, kf00, s0, 0, 0, 0);
        s0 = MFMA_F16(qf1, kf01, s0, 0, 0, 0);
        s1 = MFMA_F16(qf0, kf10, s1, 0, 0, 0);
        s1 = MFMA_F16(qf1, kf11, s1, 0, 0, 0);

        float alpha[4];
        #pragma unroll
        for (int r = 0; r < 4; ++r) {
            float t0 = s0[r] * CS, t1 = s1[r] * CS;
            float v = fmaxf(t0, t1);
            v = fmaxf(v, __shfl_xor(v, 1));
            v = fmaxf(v, __shfl_xor(v, 2));
            v = fmaxf(v, __shfl_xor(v, 4));
            v = fmaxf(v, __shfl_xor(v, 8));
            float mn = fmaxf(mr[r], v);
            alpha[r] = __builtin_exp2f(mr[r] - mn);
            mr[r] = mn;
            float p0 = __builtin_exp2f(t0 - mn);
            float p1 = __builtin_exp2f(t1 - mn);
            float ss = p0 + p1;
            ss += __shfl_xor(ss, 1);
            ss += __shfl_xor(ss, 2);
            ss += __shfl_xor(ss, 4);
            ss += __shfl_xor(ss, 8);
            lr[r] = lr[r] * alpha[r] + ss;
            lp[wv][quad * 4 + r][l15]      = (_Float16)p0;
            lp[wv][quad * 4 + r][16 + l15] = (_Float16)p1;
        }
        #pragma unroll
        for (int vt = 0; vt < 4; ++vt) {
            #pragma unroll
            for (int r = 0; r < 4; ++r) o[vt][r] *= alpha[r];
        }
        half8 pf = *(const half8*)&lp[wv][l15][quad * 8];
        #pragma unroll
        for (int vt = 0; vt < 4; ++vt) {
            half8 vf = *(const half8*)&lvt[vt * 16 + l15][quad * 8];
            o[vt] = MFMA_F16(pf, vf, o[vt], 0, 0, 0);
        }
    }

    #pragma unroll
    for (int vt = 0; vt < 4; ++vt) {
        #pragma unroll
        for (int r = 0; r < 4; ++r) {
            int rowl = wv * 16 + quad * 4 + r;
            int j = qt * 64 + rowl;
            float w;
            if (n == 0 || n == 15)  w = 1.0f;
            else if (j < 64)        w = (float)j * (1.0f / 63.0f);
            else if (j >= 448)      w = (float)(511 - j) * (1.0f / 63.0f);
            else                    w = 1.0f;
            float sc = w / (w + 1e-8f);
            Ob[rowl * 64 + vt * 16 + l15] = o[vt][r] / lr[r] * sc;
        }
    }
}

extern "C" void kernel_launch(void* const* d_in, const int* in_sizes, int n_in,
                              void* d_out, int out_size, void* d_ws, size_t ws_size,
                              hipStream_t stream) {
    const float* q   = (const float*)d_in[0];
    const float* k   = (const float*)d_in[1];
    const float* v   = (const float*)d_in[2];
    const int*   pid = (const int*)d_in[3];
    float* out = (float*)d_out;
    (void)in_sizes; (void)n_in; (void)out_size;

    const size_t need = 2097152ull + 33554432ull + 33554432ull; // tab + Kr + Vt
    if (ws_size >= need) {
        float*    tab = (float*)d_ws;
        _Float16* Kr  = (_Float16*)((char*)d_ws + 2097152);
        _Float16* Vt  = (_Float16*)((char*)d_ws + 2097152 + 33554432);
        table_k<<<dim3(1024), dim3(256), 0, stream>>>(pid, tab);
        kprep  <<<dim3(4096), dim3(256), 0, stream>>>(k, tab, Kr);
        vprep  <<<dim3(8192), dim3(256), 0, stream>>>(v, Vt);
        swa2   <<<dim3(4096), dim3(256), 0, stream>>>(q, Kr, Vt, tab, out);
    } else {
        swa_fb<<<dim3(4096), dim3(256), 0, stream>>>(q, k, v, pid, out);
    }
}

// Round 3
// 268.625 us; speedup vs baseline: 1.2838x; 1.0728x over previous
//
#include <hip/hip_runtime.h>

typedef _Float16 half8 __attribute__((ext_vector_type(8)));
typedef _Float16 half4 __attribute__((ext_vector_type(4)));
typedef float floatx4 __attribute__((ext_vector_type(4)));

#define MFMA_F16 __builtin_amdgcn_mfma_f32_16x16x32_f16
#define FREQ (-0.41524101186092f)   // -log2(10000)/32

// B=2,H=16,L=8192,D=64,WINDOW=512. Grid 1024: block = half-window (256 q rows),
// wave = 64 q rows (4 row-tiles). Window's two blocks are 8 apart -> same XCD.
__global__ __launch_bounds__(256) void swa3(
    const float* __restrict__ Q, const float* __restrict__ K,
    const float* __restrict__ V, const int* __restrict__ pid,
    float* __restrict__ Out)
{
    __shared__ __align__(16) _Float16 lq[64 * 72];    // Q rope staging (reused 4x)
    __shared__ __align__(16) _Float16 lk[32 * 64];    // roped K chunk, XOR-swizzled
    __shared__ __align__(16) _Float16 lvt[64 * 32];   // V^T chunk, XOR-swizzled
    __shared__ __align__(16) _Float16 lp[4][16 * 40]; // per-wave P buffer

    const int bid   = blockIdx.x;
    const int half_ = (bid >> 3) & 1;                  // which half-window
    const int win   = (bid & 7) | ((bid >> 4) << 3);   // 0..511
    const int n = win & 15, bh = win >> 4;
    const long long winrow = (long long)bh * 8192 + n * 512;
    const long long qbase  = winrow + half_ * 256;
    const float* Qb = Q + qbase * 64;
    const float* Kb = K + winrow * 64;
    const float* Vb = V + winrow * 64;
    float* Ob = Out + qbase * 64;
    const int pidq = n * 512 + half_ * 256;
    const int pidk = n * 512;

    const int tid = threadIdx.x, lane = tid & 63, wv = tid >> 6;
    const int l15 = lane & 15, quad = lane >> 4;
    const float CS = 0.125f * 1.44269504088896f;       // 1/sqrt(D)*log2(e)

    // ---------- Q fragments: 4 rounds of 64 rows through lq ----------
    half8 qf[4][2];
    {
        const int rowl = tid >> 2;          // 0..63 within round
        const int dq   = (tid & 3) * 8;     // pair-dim start
        float ifq[8];
        #pragma unroll
        for (int i = 0; i < 8; ++i) ifq[i] = __builtin_exp2f((float)(dq + i) * FREQ);
        for (int rnd = 0; rnd < 4; ++rnd) {
            const float* src = Qb + (rnd * 64 + rowl) * 64;
            float pos = (float)pid[pidq + rnd * 64 + rowl];
            float4 a0 = *(const float4*)(src + dq);
            float4 a1 = *(const float4*)(src + dq + 4);
            float4 b0 = *(const float4*)(src + 32 + dq);
            float4 b1 = *(const float4*)(src + 36 + dq);
            float lo[8] = {a0.x,a0.y,a0.z,a0.w,a1.x,a1.y,a1.z,a1.w};
            float hi[8] = {b0.x,b0.y,b0.z,b0.w,b1.x,b1.y,b1.z,b1.w};
            half8 wlo, whi;
            #pragma unroll
            for (int i = 0; i < 8; ++i) {
                float sn, cn;
                __sincosf(pos * ifq[i], &sn, &cn);
                wlo[i] = (_Float16)((lo[i] * cn - hi[i] * sn) * CS);
                whi[i] = (_Float16)((hi[i] * cn + lo[i] * sn) * CS);
            }
            if (rnd) __syncthreads();       // prior round's frag reads done
            *(half8*)&lq[rowl * 72 + dq]      = wlo;
            *(half8*)&lq[rowl * 72 + 32 + dq] = whi;
            __syncthreads();
            if (wv == rnd) {
                #pragma unroll
                for (int rt = 0; rt < 4; ++rt) {
                    qf[rt][0] = *(const half8*)&lq[(rt * 16 + l15) * 72 + quad * 8];
                    qf[rt][1] = *(const half8*)&lq[(rt * 16 + l15) * 72 + 32 + quad * 8];
                }
            }
        }
    }

    floatx4 o[4][4], ol[4];
    #pragma unroll
    for (int rt = 0; rt < 4; ++rt) {
        ol[rt] = (floatx4){0.f, 0.f, 0.f, 0.f};
        #pragma unroll
        for (int vt = 0; vt < 4; ++vt) o[rt][vt] = (floatx4){0.f, 0.f, 0.f, 0.f};
    }
    half8 onesf;
    #pragma unroll
    for (int i = 0; i < 8; ++i) onesf[i] = (_Float16)1.0f;

    // staging roles
    const int key = tid >> 3;            // 0..31 (K rope)
    const int d0  = (tid & 7) * 4;       // 0..28
    const int dv  = tid & 63;            // V gather column
    const int k8  = (tid >> 6) & 3;      // V key-octet
    float if4[4];
    #pragma unroll
    for (int i = 0; i < 4; ++i) if4[i] = __builtin_exp2f((float)(d0 + i) * FREQ);
    const int klo_addr = key * 64 + (((d0 >> 3) ^ (key & 7)) * 8) + (d0 & 7);
    const int khi_addr = key * 64 + ((((d0 >> 3) + 4) ^ (key & 7)) * 8) + (d0 & 7);
    const int vst_addr = dv * 32 + (k8 ^ ((dv >> 1) & 3)) * 8;
    const int ksw0 = (quad ^ (l15 & 7)) * 8;
    const int ksw1 = ((quad + 4) ^ (l15 & 7)) * 8;
    const int vsw  = (quad ^ ((l15 >> 1) & 3)) * 8;

    // prologue: prefetch chunk 0
    float4 ka = *(const float4*)(Kb + key * 64 + d0);
    float4 kb2 = *(const float4*)(Kb + key * 64 + 32 + d0);
    float vr[8];
    #pragma unroll
    for (int i = 0; i < 8; ++i) vr[i] = Vb[(k8 * 8 + i) * 64 + dv];

    for (int kc = 0; kc < 16; ++kc) {
        // rope K regs -> f16
        float kpos = (float)pid[pidk + kc * 32 + key];
        half4 klo, khi;
        {
            float a[4] = {ka.x, ka.y, ka.z, ka.w};
            float b[4] = {kb2.x, kb2.y, kb2.z, kb2.w};
            #pragma unroll
            for (int i = 0; i < 4; ++i) {
                float sn, cn;
                __sincosf(kpos * if4[i], &sn, &cn);
                klo[i] = (_Float16)(a[i] * cn - b[i] * sn);
                khi[i] = (_Float16)(b[i] * cn + a[i] * sn);
            }
        }
        half8 vh;
        #pragma unroll
        for (int i = 0; i < 8; ++i) vh[i] = (_Float16)vr[i];

        __syncthreads();                  // prior iter's frag reads done
        *(half4*)&lk[klo_addr] = klo;
        *(half4*)&lk[khi_addr] = khi;
        *(half8*)&lvt[vst_addr] = vh;
        __syncthreads();

        // prefetch next chunk while computing this one
        if (kc < 15) {
            const float* kn = Kb + (kc + 1) * 2048;
            const float* vn = Vb + (kc + 1) * 2048;
            ka  = *(const float4*)(kn + key * 64 + d0);
            kb2 = *(const float4*)(kn + key * 64 + 32 + d0);
            #pragma unroll
            for (int i = 0; i < 8; ++i) vr[i] = vn[(k8 * 8 + i) * 64 + dv];
        }

        // fragments (shared across row-tiles)
        half8 kf00 = *(const half8*)&lk[l15 * 64 + ksw0];
        half8 kf01 = *(const half8*)&lk[l15 * 64 + ksw1];
        half8 kf10 = *(const half8*)&lk[(16 + l15) * 64 + ksw0];
        half8 kf11 = *(const half8*)&lk[(16 + l15) * 64 + ksw1];
        half8 vf[4];
        #pragma unroll
        for (int vt = 0; vt < 4; ++vt)
            vf[vt] = *(const half8*)&lvt[(vt * 16 + l15) * 32 + vsw];

        #pragma unroll
        for (int rt = 0; rt < 4; ++rt) {
            floatx4 s0 = {0.f,0.f,0.f,0.f}, s1 = {0.f,0.f,0.f,0.f};
            s0 = MFMA_F16(qf[rt][0], kf00, s0, 0, 0, 0);
            s0 = MFMA_F16(qf[rt][1], kf01, s0, 0, 0, 0);
            s1 = MFMA_F16(qf[rt][0], kf10, s1, 0, 0, 0);
            s1 = MFMA_F16(qf[rt][1], kf11, s1, 0, 0, 0);

            #pragma unroll
            for (int r = 0; r < 4; ++r) {
                float p0 = __builtin_exp2f(s0[r]);
                float p1 = __builtin_exp2f(s1[r]);
                lp[wv][(quad * 4 + r) * 40 + l15]      = (_Float16)p0;
                lp[wv][(quad * 4 + r) * 40 + 16 + l15] = (_Float16)p1;
            }
            half8 pf = *(const half8*)&lp[wv][l15 * 40 + quad * 8];
            ol[rt] = MFMA_F16(pf, onesf, ol[rt], 0, 0, 0);
            #pragma unroll
            for (int vt = 0; vt < 4; ++vt)
                o[rt][vt] = MFMA_F16(pf, vf[vt], o[rt][vt], 0, 0, 0);
        }
    }

    // ---------- epilogue ----------
    #pragma unroll
    for (int rt = 0; rt < 4; ++rt) {
        #pragma unroll
        for (int r = 0; r < 4; ++r) {
            int rowl = wv * 64 + rt * 16 + quad * 4 + r;   // 0..255
            int j = half_ * 256 + rowl;                    // row within window
            float w;
            if (n == 0 || n == 15)  w = 1.0f;
            else if (j < 64)        w = (float)j * (1.0f / 63.0f);
            else if (j >= 448)      w = (float)(511 - j) * (1.0f / 63.0f);
            else                    w = 1.0f;
            float f = (w / (w + 1e-8f)) / ol[rt][r];
            #pragma unroll
            for (int vt = 0; vt < 4; ++vt)
                Ob[rowl * 64 + vt * 16 + l15] = o[rt][vt][r] * f;
        }
    }
}

extern "C" void kernel_launch(void* const* d_in, const int* in_sizes, int n_in,
                              void* d_out, int out_size, void* d_ws, size_t ws_size,
                              hipStream_t stream) {
    const float* q   = (const float*)d_in[0];
    const float* k   = (const float*)d_in[1];
    const float* v   = (const float*)d_in[2];
    const int*   pid = (const int*)d_in[3];
    float* out = (float*)d_out;
    (void)in_sizes; (void)n_in; (void)out_size; (void)d_ws; (void)ws_size;
    swa3<<<dim3(1024), dim3(256), 0, stream>>>(q, k, v, pid, out);
}